// Round 8
// baseline (312.907 us; speedup 1.0000x reference)
//
#include <hip/hip_runtime.h>

#define DEVINL __device__ __forceinline__

typedef __bf16 bf16x8 __attribute__((ext_vector_type(8)));
typedef float  f32x4  __attribute__((ext_vector_type(4)));

// ---------------- constants / ws layout ----------------
// B=256, C=1024, H=64, E=64, K=2, MI=128, tokens T = 262144
static constexpr size_t kAdjOff  = 0;                 // 2*1024 f32 (8 KB)
static constexpr size_t kBiasOff = 8192;              // 64*3*4*64*4 f32 = 786432 B
static constexpr size_t kFragOff = 8192 + 786432;     // 112 frags * 1024 B = 114688 B

// B-fragment bases (units: one frag = 64 lanes * 16 B)
static constexpr int FB_Wn1h0 = 0,  FB_Wn1h1 = 8,  FB_Wn2_0 = 16, FB_Wn2_1 = 24;
static constexpr int FB_Ws1h  = 32, FB_Ws2   = 40, FB_We    = 48, FB_Wa    = 56;
static constexpr int FB_Wih   = 64, FB_Whh   = 88;

// ---------------- helpers ----------------
DEVINL unsigned short bf16r(float f) {           // RTNE float->bf16
  unsigned u = __builtin_bit_cast(unsigned, f);
  unsigned r = ((u >> 16) & 1u) + 0x7FFFu;
  return (unsigned short)((u + r) >> 16);
}
DEVINL float sigmoidf_(float x) { return __builtin_amdgcn_rcpf(1.f + __expf(-x)); }
DEVINL float tanhf_(float x)    { return 1.f - 2.f * __builtin_amdgcn_rcpf(1.f + __expf(2.f * x)); }

DEVINL void lds_fence() {  // wave-local: drain LDS ops; stop compiler motion across
  __builtin_amdgcn_sched_barrier(0);
  __builtin_amdgcn_s_waitcnt(0xC07F);   // lgkmcnt(0), vmcnt/expcnt untouched
  __builtin_amdgcn_sched_barrier(0);
}

DEVINL f32x4 mfma16(bf16x8 a, bf16x8 b, f32x4 c) {
  return __builtin_amdgcn_mfma_f32_16x16x32_bf16(a, b, c, 0, 0, 0);
}

DEVINL unsigned clip2_(unsigned x) {   // clamp two packed bf16 to [-5,5]; exact repack
  float lo = __builtin_bit_cast(float, x << 16);
  float hi = __builtin_bit_cast(float, x & 0xFFFF0000u);
  lo = fminf(fmaxf(lo, -5.f), 5.f);
  hi = fminf(fmaxf(hi, -5.f), 5.f);
  return (__builtin_bit_cast(unsigned, lo) >> 16) | (__builtin_bit_cast(unsigned, hi) & 0xFFFF0000u);
}
DEVINL bf16x8 clip5(bf16x8 a) {
  uint4 u = __builtin_bit_cast(uint4, a);
  u.x = clip2_(u.x); u.y = clip2_(u.y); u.z = clip2_(u.z); u.w = clip2_(u.w);
  return __builtin_bit_cast(bf16x8, u);
}

// ---------------- prep 1: adjacency vector (SPARSE: a0 has ~5 nonzeros) ----------------
__global__ void prep_adj_kernel(const int* __restrict__ qt, const float* __restrict__ onehot,
                                const float* __restrict__ graphs, float* __restrict__ adjw) {
  __shared__ float a0v[1024];
  __shared__ int   aidx[1024];
  __shared__ int   s_nnz;
  __shared__ float s_den;
  const int tid = threadIdx.x;
  const int k = blockIdx.x >> 2, chunk = blockIdx.x & 3;   // 8 blocks: 2k x 4 chunks of 256 d
  if (tid == 0) { s_nnz = 0; s_den = 0.f; }
  __syncthreads();
  const int q0 = qt[0];
  float lsum = 0.f;
#pragma unroll
  for (int i = 0; i < 4; i++) {
    int c = tid * 4 + i;
    float v = onehot[(size_t)q0 * 1024 + c];
    lsum += v;
    if (v != 0.f) { int p = atomicAdd(&s_nnz, 1); aidx[p] = c; a0v[p] = v; }
  }
#pragma unroll
  for (int off = 32; off >= 1; off >>= 1) lsum += __shfl_xor(lsum, off, 64);
  if ((tid & 63) == 0) atomicAdd(&s_den, lsum);
  __syncthreads();
  const float denom = fmaxf(s_den, 1.f);
  const int nnz = s_nnz;
  const int d = chunk * 256 + tid;
  const float* G = graphs + (size_t)k * 1048576 + d;
  float sum = 0.f;
  for (int j = 0; j < nnz; j++) sum += a0v[j] * G[(size_t)aidx[j] * 1024];
  adjw[k * 1024 + d] = fminf(fmaxf(sum / denom, -5.f), 5.f);
}

// ---------------- prep 2: per-c bias tables (kc folded into layer-1 bias) ----------------
// biasTab layout: [c16(64)][tab(3: n_k0,n_k1,self)][nt(4)][lane(64)][r(4)] fp32
__global__ void prep_bias_kernel(const float* __restrict__ kc, const float* __restrict__ Wn1,
                                 const float* __restrict__ bn1, const float* __restrict__ Ws1,
                                 const float* __restrict__ bs1, float* __restrict__ biasTab) {
  int gid = blockIdx.x * 256 + threadIdx.x;   // 196608 total
  int j = gid & 63;
  int c = (gid >> 6) & 1023;
  int tab = gid >> 16;                        // 0,1 neigh-k; 2 self
  const float* kcr = kc + (size_t)c * 64;
  float s;
  if (tab < 2) {
    s = bn1[tab * 64 + j];
    const float* W = Wn1 + ((size_t)tab * 256 + 192) * 64 + j;   // kc rows of neigh net
#pragma unroll 4
    for (int e = 0; e < 64; e++) s += fminf(fmaxf(kcr[e], -5.f), 5.f) * W[(size_t)e * 64];
  } else {
    s = bs1[j];
    const float* W = Ws1 + (size_t)64 * 64 + j;                  // kc rows of self net (unclipped)
#pragma unroll 4
    for (int e = 0; e < 64; e++) s += kcr[e] * W[(size_t)e * 64];
  }
  int c16 = c >> 4, rr = c & 3, qq = (c & 15) >> 2, nt = j >> 4;
  int lane = qq * 16 + (j & 15);
  biasTab[(size_t)((((c16 * 3 + tab) * 4 + nt) * 64 + lane)) * 4 + rr] = s;
}

// ---------------- prep 3: weights -> bf16 B-fragments (pre-swizzled) ----------------
// B-frag (16x16x32): lane l holds B[k = ks*32 + (l>>4)*8 + j][n = nt*16 + (l&15)], j=0..7
__global__ void prep_wfrag_kernel(const float* __restrict__ Wn1, const float* __restrict__ Wn2,
                                  const float* __restrict__ Ws1, const float* __restrict__ Ws2,
                                  const float* __restrict__ We,  const float* __restrict__ Wa,
                                  const float* __restrict__ Wih, const float* __restrict__ Whh,
                                  uint4* __restrict__ wfrag) {
  const int bid = blockIdx.x, lane = threadIdx.x;   // 112 blocks x 64 threads
  int mat, ks, nt;
  if (bid < 64) { mat = bid >> 3; ks = (bid >> 2) & 1; nt = bid & 3; }
  else { int f2 = bid - 64; mat = 8 + f2 / 24; int f = f2 % 24; ks = f / 12; nt = f % 12; }
  const float* base = Wn1; int stride = 64;
  switch (mat) {
    case 0: base = Wn1 + (size_t)128 * 64; break;          // Wn1 k0, ht rows 128..191
    case 1: base = Wn1 + (size_t)(256 + 128) * 64; break;  // Wn1 k1
    case 2: base = Wn2; break;
    case 3: base = Wn2 + (size_t)64 * 64; break;
    case 4: base = Ws1; break;                             // rows 0..63 (ht part)
    case 5: base = Ws2; break;
    case 6: base = We; break;
    case 7: base = Wa; break;
    case 8: base = Wih; stride = 192; break;
    case 9: base = Whh; stride = 192; break;
  }
  const int qq = lane >> 4, col = nt * 16 + (lane & 15);
  union { unsigned short u[8]; uint4 v; } tmp;
#pragma unroll
  for (int jj = 0; jj < 8; jj++) {
    int k = ks * 32 + qq * 8 + jj;
    tmp.u[jj] = bf16r(base[(size_t)k * stride + col]);
  }
  wfrag[(size_t)bid * 64 + lane] = tmp.v;
}

// ---------------- main fused kernel ----------------
// block = 256 threads = 4 waves; each wave owns 32 tokens (2 MFMA m-tiles), no inter-wave sync.
// REGISTER MODEL (rounds 3/6/7): caps BELOW the structural peak spill 300-500 MB.
// This version LOWERS the structural peak instead: mt-sequential res + PASS-SPLIT GRU
// (r/z gates -> sigmoid to 32 regs -> n/h gates; peak accs 64 not 128). Estimated
// unified peak ~110-140, so __launch_bounds__(256,3) (cap 170) is above the need ->
// 3 blocks/CU without spill. GATE: WRITE_SIZE must stay ~1 MB.
__global__ __launch_bounds__(256, 3) void gkt_main_kernel(
    const int* __restrict__ qt, const float* __restrict__ onehot, const float* __restrict__ ht,
    const float* __restrict__ nw, const float* __restrict__ bn2, const float* __restrict__ be,
    const float* __restrict__ ba, const float* __restrict__ bih, const float* __restrict__ bhh,
    const float* __restrict__ Wp, const float* __restrict__ bp, const float* __restrict__ eaw,
    const float* __restrict__ bs2, const float* __restrict__ adjw, const float* __restrict__ biasTab,
    const bf16x8* __restrict__ wfrag, float* __restrict__ out) {
  __shared__ __align__(16) unsigned short hbuf[4][32][72];  // per-wave stage scratch, bf16, pitch 72
  __shared__ __align__(16) float tokp[4][128];              // [wave][mask|adj0|adj1|g][32]

  const int tid = threadIdx.x;
  const int wv = tid >> 6, lane = tid & 63;
  const int q = lane >> 4, cl = lane & 15;
  const int t0 = (blockIdx.x * 4 + wv) * 32;
  const int b = t0 >> 10, c0 = t0 & 1023, c16 = c0 >> 4;

  unsigned short* hb = &hbuf[wv][0][0];
  float* tp = &tokp[wv][0];

  // ---- staging: per-token params + ht rows (coalesced float4) ----
  if (lane < 32) {
    const int c = c0 + lane;
    tp[lane]      = onehot[(size_t)qt[b] * 1024 + c];  // mask
    tp[32 + lane] = adjw[c];                           // adj[0][c]
    tp[64 + lane] = adjw[1024 + c];                    // adj[1][c]
    tp[96 + lane] = eaw[c];                            // g
  }
  {
    const float4* ht4 = (const float4*)ht;
#pragma unroll
    for (int i = 0; i < 8; i++) {
      float4 v = ht4[(size_t)t0 * 16 + i * 64 + lane];
      int e = i * 64 + lane;
      int tok = e >> 4, coll = (e & 15) * 4;
      ushort4 h;
      h.x = bf16r(v.x); h.y = bf16r(v.y); h.z = bf16r(v.z); h.w = bf16r(v.w);
      *(ushort4*)&hbuf[wv][tok][coll] = h;
    }
  }
  lds_fence();

  const float wmix = fminf(fmaxf(nw[0], 0.1f), 0.9f);
  float wp4[4];
#pragma unroll
  for (int nt = 0; nt < 4; nt++) wp4[nt] = Wp[nt * 16 + cl];
  const float bpv = bp[0];

  auto ldA = [&](int mt, int ks) -> bf16x8 {
    return *(const bf16x8*)(hb + (cl + 16 * mt) * 72 + ks * 32 + q * 8);
  };
  auto ldB = [&](int frag) -> bf16x8 { return wfrag[frag * 64 + lane]; };
  auto ldTP4 = [&](int base, int mt) -> f32x4 {   // 4 consecutive token params (r=0..3)
    return *(const f32x4*)(tp + base + 16 * mt + q * 4);
  };
  const f32x4* bt4 = (const f32x4*)biasTab;

  // ---- read raw ht A-frags into registers (live through GRU) ----
  bf16x8 xr[2][2];
#pragma unroll
  for (int mt = 0; mt < 2; mt++)
#pragma unroll
    for (int ks = 0; ks < 2; ks++) xr[mt][ks] = ldA(mt, ks);
  lds_fence();   // reads drained; hbuf free for reuse

  // ---- neighbor path (always; for mask==1 tokens result is discarded later) ----
  f32x4 nf[2][4];
  {
    bf16x8 xc[2][2];
#pragma unroll
    for (int mt = 0; mt < 2; mt++)
#pragma unroll
      for (int ks = 0; ks < 2; ks++) xc[mt][ks] = clip5(xr[mt][ks]);

#pragma unroll
    for (int k2 = 0; k2 < 2; k2++) {
      f32x4 acc[2][4];
#pragma unroll
      for (int mt = 0; mt < 2; mt++)
#pragma unroll
        for (int nt = 0; nt < 4; nt++)
          acc[mt][nt] = bt4[(((c16 + mt) * 3 + k2) * 4 + nt) * 64 + lane];  // kc part + bn1
#pragma unroll
      for (int ks = 0; ks < 2; ks++)
#pragma unroll
        for (int nt = 0; nt < 4; nt++) {
          bf16x8 bb = ldB((k2 ? FB_Wn1h1 : FB_Wn1h0) + ks * 4 + nt);
          acc[0][nt] = mfma16(xc[0][ks], bb, acc[0][nt]);
          acc[1][nt] = mfma16(xc[1][ks], bb, acc[1][nt]);
        }
#pragma unroll
      for (int mt = 0; mt < 2; mt++)
#pragma unroll
        for (int nt = 0; nt < 4; nt++)
#pragma unroll
          for (int r = 0; r < 4; r++)
            hb[(16 * mt + q * 4 + r) * 72 + nt * 16 + cl] = bf16r(fmaxf(acc[mt][nt][r], 0.f));
      lds_fence();
      f32x4 acc2[2][4];
#pragma unroll
      for (int nt = 0; nt < 4; nt++) {
        float bz = bn2[k2 * 64 + nt * 16 + cl];
        f32x4 iv = {bz, bz, bz, bz};
        acc2[0][nt] = iv; acc2[1][nt] = iv;
      }
#pragma unroll
      for (int ks = 0; ks < 2; ks++) {
        bf16x8 a0 = ldA(0, ks), a1 = ldA(1, ks);
#pragma unroll
        for (int nt = 0; nt < 4; nt++) {
          bf16x8 bb = ldB((k2 ? FB_Wn2_1 : FB_Wn2_0) + ks * 4 + nt);
          acc2[0][nt] = mfma16(a0, bb, acc2[0][nt]);
          acc2[1][nt] = mfma16(a1, bb, acc2[1][nt]);
        }
      }
      lds_fence();   // layer-2 reads drained before next overwrite of hbuf
#pragma unroll
      for (int mt = 0; mt < 2; mt++) {
        f32x4 adjv = ldTP4((1 + k2) * 32, mt);
#pragma unroll
        for (int nt = 0; nt < 4; nt++)
#pragma unroll
          for (int r = 0; r < 4; r++) {
            float nb = fminf(fmaxf(acc2[mt][nt][r], 0.f), 5.f);      // relu then clip
            float v = adjv[r] * nb;                                  // adj[k][c] * nb
            if (k2 == 0) nf[mt][nt][r] = wmix * fminf(fmaxf(v, -5.f), 5.f);
            else         nf[mt][nt][r] = fminf(fmaxf(nf[mt][nt][r] + (1.f - wmix) * v, -5.f), 5.f);
          }
      }
    }
  }

  // ---- self path (only if any of this wave's 32 tokens has mask==1) ----
  bool anySelf = __any((lane < 32) && (tp[lane] > 0.5f));
  if (anySelf) {
    f32x4 acc[2][4];
#pragma unroll
    for (int mt = 0; mt < 2; mt++)
#pragma unroll
      for (int nt = 0; nt < 4; nt++)
        acc[mt][nt] = bt4[(((c16 + mt) * 3 + 2) * 4 + nt) * 64 + lane];
#pragma unroll
    for (int ks = 0; ks < 2; ks++)
#pragma unroll
      for (int nt = 0; nt < 4; nt++) {
        bf16x8 bb = ldB(FB_Ws1h + ks * 4 + nt);
        acc[0][nt] = mfma16(xr[0][ks], bb, acc[0][nt]);    // raw (unclipped) ht
        acc[1][nt] = mfma16(xr[1][ks], bb, acc[1][nt]);
      }
#pragma unroll
    for (int mt = 0; mt < 2; mt++)
#pragma unroll
      for (int nt = 0; nt < 4; nt++)
#pragma unroll
        for (int r = 0; r < 4; r++)
          hb[(16 * mt + q * 4 + r) * 72 + nt * 16 + cl] = bf16r(fmaxf(acc[mt][nt][r], 0.f));
    lds_fence();
    f32x4 acc2[2][4];
#pragma unroll
    for (int nt = 0; nt < 4; nt++) {
      float bz = bs2[nt * 16 + cl];
      f32x4 iv = {bz, bz, bz, bz};
      acc2[0][nt] = iv; acc2[1][nt] = iv;
    }
#pragma unroll
    for (int ks = 0; ks < 2; ks++) {
      bf16x8 a0 = ldA(0, ks), a1 = ldA(1, ks);
#pragma unroll
      for (int nt = 0; nt < 4; nt++) {
        bf16x8 bb = ldB(FB_Ws2 + ks * 4 + nt);
        acc2[0][nt] = mfma16(a0, bb, acc2[0][nt]);
        acc2[1][nt] = mfma16(a1, bb, acc2[1][nt]);
      }
    }
    lds_fence();
#pragma unroll
    for (int mt = 0; mt < 2; mt++) {
      f32x4 mk = ldTP4(0, mt);
#pragma unroll
      for (int nt = 0; nt < 4; nt++)
#pragma unroll
        for (int r = 0; r < 4; r++) {
          float sf = fminf(fmaxf(acc2[mt][nt][r], 0.f), 10.f);   // relu, clip +-10
          nf[mt][nt][r] = (mk[r] > 0.5f) ? sf : nf[mt][nt][r];   // m_next select (clip50 identity)
        }
    }
  }

  // ---- res = m - g*sigmoid(m@We+be)*m + g*tanh(m@Wa+ba)  (mt-sequential) ----
#pragma unroll
  for (int mt = 0; mt < 2; mt++)
#pragma unroll
    for (int nt = 0; nt < 4; nt++)
#pragma unroll
      for (int r = 0; r < 4; r++)
        hb[(16 * mt + q * 4 + r) * 72 + nt * 16 + cl] = bf16r(nf[mt][nt][r]);  // m_next (bf16)
  lds_fence();
#pragma unroll
  for (int mt = 0; mt < 2; mt++) {
    bf16x8 mf0 = ldA(mt, 0), mf1 = ldA(mt, 1);
    f32x4 gv = ldTP4(96, mt);
    {
      f32x4 accE[4];
#pragma unroll
      for (int nt = 0; nt < 4; nt++) {
        float bz = be[nt * 16 + cl];
        accE[nt] = {bz, bz, bz, bz};
      }
#pragma unroll
      for (int nt = 0; nt < 4; nt++) {
        accE[nt] = mfma16(mf0, ldB(FB_We + nt), accE[nt]);
        accE[nt] = mfma16(mf1, ldB(FB_We + 4 + nt), accE[nt]);
      }
#pragma unroll
      for (int nt = 0; nt < 4; nt++)
#pragma unroll
        for (int r = 0; r < 4; r++) {
          float m = nf[mt][nt][r];
          nf[mt][nt][r] = m - gv[r] * sigmoidf_(accE[nt][r]) * m;
        }
    }
    {
      f32x4 accA[4];
#pragma unroll
      for (int nt = 0; nt < 4; nt++) {
        float bz = ba[nt * 16 + cl];
        accA[nt] = {bz, bz, bz, bz};
      }
#pragma unroll
      for (int nt = 0; nt < 4; nt++) {
        accA[nt] = mfma16(mf0, ldB(FB_Wa + nt), accA[nt]);
        accA[nt] = mfma16(mf1, ldB(FB_Wa + 4 + nt), accA[nt]);
      }
#pragma unroll
      for (int nt = 0; nt < 4; nt++)
#pragma unroll
        for (int r = 0; r < 4; r++)
          nf[mt][nt][r] += gv[r] * tanhf_(accA[nt][r]);   // nf now holds res
    }
  }

  // ---- GRU gates + output (mt-sequential, PASS-SPLIT: r/z then n/h) ----
  lds_fence();   // all mf reads drained before res overwrite
#pragma unroll
  for (int mt = 0; mt < 2; mt++)
#pragma unroll
    for (int nt = 0; nt < 4; nt++)
#pragma unroll
      for (int r = 0; r < 4; r++)
        hb[(16 * mt + q * 4 + r) * 72 + nt * 16 + cl] = bf16r(nf[mt][nt][r]);  // res (bf16)
  lds_fence();

#pragma unroll
  for (int mt = 0; mt < 2; mt++) {
    bf16x8 rf0 = ldA(mt, 0), rf1 = ldA(mt, 1);
    // pass 1: r/z gates -> sigmoided into rr/zz (32 regs), accs freed
    f32x4 rr[4], zz[4];
    {
      f32x4 gR[4], gZ[4];
#pragma unroll
      for (int nt = 0; nt < 4; nt++) {
        int col = nt * 16 + cl;
        float brz = bih[col] + bhh[col];
        float bzz = bih[64 + col] + bhh[64 + col];
        gR[nt] = {brz, brz, brz, brz};
        gZ[nt] = {bzz, bzz, bzz, bzz};
      }
#pragma unroll
      for (int ks = 0; ks < 2; ks++) {
        bf16x8 rfk = ks ? rf1 : rf0;
        bf16x8 xrk = xr[mt][ks];
#pragma unroll
        for (int nt = 0; nt < 4; nt++) {
          gR[nt] = mfma16(rfk, ldB(FB_Wih + ks * 12 + nt), gR[nt]);
          gR[nt] = mfma16(xrk, ldB(FB_Whh + ks * 12 + nt), gR[nt]);   // gi_r + gh_r chained
          gZ[nt] = mfma16(rfk, ldB(FB_Wih + ks * 12 + 4 + nt), gZ[nt]);
          gZ[nt] = mfma16(xrk, ldB(FB_Whh + ks * 12 + 4 + nt), gZ[nt]);
        }
      }
#pragma unroll
      for (int nt = 0; nt < 4; nt++)
#pragma unroll
        for (int r = 0; r < 4; r++) {
          rr[nt][r] = sigmoidf_(gR[nt][r]);
          zz[nt][r] = sigmoidf_(gZ[nt][r]);
        }
    }
    // pass 2: n/h gates
    f32x4 gN[4], gH[4];
#pragma unroll
    for (int nt = 0; nt < 4; nt++) {
      int col = nt * 16 + cl;
      float bnn = bih[128 + col];
      float bhn = bhh[128 + col];
      gN[nt] = {bnn, bnn, bnn, bnn};
      gH[nt] = {bhn, bhn, bhn, bhn};
    }
#pragma unroll
    for (int ks = 0; ks < 2; ks++) {
      bf16x8 rfk = ks ? rf1 : rf0;
      bf16x8 xrk = xr[mt][ks];
#pragma unroll
      for (int nt = 0; nt < 4; nt++) {
        gN[nt] = mfma16(rfk, ldB(FB_Wih + ks * 12 + 8 + nt), gN[nt]);  // in_
        gH[nt] = mfma16(xrk, ldB(FB_Whh + ks * 12 + 8 + nt), gH[nt]);  // hn
      }
    }
#pragma unroll
    for (int r = 0; r < 4; r++) {
      int tok = 16 * mt + q * 4 + r;
      float part = 0.f;
#pragma unroll
      for (int nt = 0; nt < 4; nt++) {
        float nval = tanhf_(gN[nt][r] + rr[nt][r] * gH[nt][r]);
        float htv = ht[(size_t)(t0 + tok) * 64 + nt * 16 + cl];   // fp32 ht for blend
        float hnx = (1.f - zz[nt][r]) * nval + zz[nt][r] * htv;
        part += hnx * wp4[nt];
      }
      part += __shfl_xor(part, 1, 64);
      part += __shfl_xor(part, 2, 64);
      part += __shfl_xor(part, 4, 64);
      part += __shfl_xor(part, 8, 64);
      if (cl == 0) out[t0 + tok] = sigmoidf_(part + bpv);
    }
  }
}

// ---------------- launcher ----------------
extern "C" void kernel_launch(void* const* d_in, const int* in_sizes, int n_in,
                              void* d_out, int out_size, void* d_ws, size_t ws_size,
                              hipStream_t stream) {
  const int*   qt     = (const int*)d_in[1];
  const float* ht     = (const float*)d_in[2];
  const float* onehot = (const float*)d_in[3];
  const float* kc     = (const float*)d_in[4];
  const float* graphs = (const float*)d_in[5];
  const float* nw     = (const float*)d_in[6];
  const float* Ws1    = (const float*)d_in[7];
  const float* bs1    = (const float*)d_in[8];
  const float* Ws2    = (const float*)d_in[9];
  const float* bs2    = (const float*)d_in[10];
  const float* Wn1    = (const float*)d_in[11];
  const float* bn1    = (const float*)d_in[12];
  const float* Wn2    = (const float*)d_in[13];
  const float* bn2    = (const float*)d_in[14];
  const float* eaw    = (const float*)d_in[15];
  const float* We     = (const float*)d_in[16];
  const float* be     = (const float*)d_in[17];
  const float* Wa     = (const float*)d_in[18];
  const float* ba     = (const float*)d_in[19];
  const float* Wih    = (const float*)d_in[20];
  const float* bih    = (const float*)d_in[21];
  const float* Whh    = (const float*)d_in[22];
  const float* bhh    = (const float*)d_in[23];
  const float* Wp     = (const float*)d_in[24];
  const float* bp     = (const float*)d_in[25];
  float* out = (float*)d_out;

  float* adjw    = (float*)((char*)d_ws + kAdjOff);
  float* biasTab = (float*)((char*)d_ws + kBiasOff);
  uint4* wfragU  = (uint4*)((char*)d_ws + kFragOff);

  prep_adj_kernel<<<8, 256, 0, stream>>>(qt, onehot, graphs, adjw);
  prep_bias_kernel<<<768, 256, 0, stream>>>(kc, Wn1, bn1, Ws1, bs1, biasTab);
  prep_wfrag_kernel<<<112, 64, 0, stream>>>(Wn1, Wn2, Ws1, Ws2, We, Wa, Wih, Whh, wfragU);
  gkt_main_kernel<<<2048, 256, 0, stream>>>(qt, onehot, ht, nw, bn2, be, ba, bih, bhh,
                                            Wp, bp, eaw, bs2, adjw, biasTab,
                                            (const bf16x8*)wfragU, out);
}

// Round 9
// 267.422 us; speedup vs baseline: 1.1701x; 1.1701x over previous
//
#include <hip/hip_runtime.h>

#define DEVINL __device__ __forceinline__

typedef __bf16 bf16x8 __attribute__((ext_vector_type(8)));
typedef float  f32x4  __attribute__((ext_vector_type(4)));

// ---------------- constants / ws layout ----------------
// B=256, C=1024, H=64, E=64, K=2, MI=128, tokens T = 262144
static constexpr size_t kAdjOff  = 0;                 // 2*1024 f32 (8 KB)
static constexpr size_t kBiasOff = 8192;              // 64*3*4*64*4 f32 = 786432 B
static constexpr size_t kFragOff = 8192 + 786432;     // 112 frags * 1024 B = 114688 B

// B-fragment bases (units: one frag = 64 lanes * 16 B)
static constexpr int FB_Wn1h0 = 0,  FB_Wn1h1 = 8,  FB_Wn2_0 = 16, FB_Wn2_1 = 24;
static constexpr int FB_Ws1h  = 32, FB_Ws2   = 40, FB_We    = 48, FB_Wa    = 56;
static constexpr int FB_Wih   = 64, FB_Whh   = 88;

// ---------------- helpers ----------------
DEVINL unsigned short bf16r(float f) {           // RTNE float->bf16
  unsigned u = __builtin_bit_cast(unsigned, f);
  unsigned r = ((u >> 16) & 1u) + 0x7FFFu;
  return (unsigned short)((u + r) >> 16);
}
DEVINL float sigmoidf_(float x) { return __builtin_amdgcn_rcpf(1.f + __expf(-x)); }
DEVINL float tanhf_(float x)    { return 1.f - 2.f * __builtin_amdgcn_rcpf(1.f + __expf(2.f * x)); }

DEVINL void lds_fence() {  // wave-local: drain LDS ops; stop compiler motion across
  __builtin_amdgcn_sched_barrier(0);
  __builtin_amdgcn_s_waitcnt(0xC07F);   // lgkmcnt(0), vmcnt/expcnt untouched
  __builtin_amdgcn_sched_barrier(0);
}

DEVINL f32x4 mfma16(bf16x8 a, bf16x8 b, f32x4 c) {
  return __builtin_amdgcn_mfma_f32_16x16x32_bf16(a, b, c, 0, 0, 0);
}

DEVINL unsigned clip2_(unsigned x) {   // clamp two packed bf16 to [-5,5]; exact repack
  float lo = __builtin_bit_cast(float, x << 16);
  float hi = __builtin_bit_cast(float, x & 0xFFFF0000u);
  lo = fminf(fmaxf(lo, -5.f), 5.f);
  hi = fminf(fmaxf(hi, -5.f), 5.f);
  return (__builtin_bit_cast(unsigned, lo) >> 16) | (__builtin_bit_cast(unsigned, hi) & 0xFFFF0000u);
}
DEVINL bf16x8 clip5(bf16x8 a) {
  uint4 u = __builtin_bit_cast(uint4, a);
  u.x = clip2_(u.x); u.y = clip2_(u.y); u.z = clip2_(u.z); u.w = clip2_(u.w);
  return __builtin_bit_cast(bf16x8, u);
}

// ---------------- prep 1: adjacency vector (SPARSE: a0 has ~5 nonzeros) ----------------
__global__ void prep_adj_kernel(const int* __restrict__ qt, const float* __restrict__ onehot,
                                const float* __restrict__ graphs, float* __restrict__ adjw) {
  __shared__ float a0v[1024];
  __shared__ int   aidx[1024];
  __shared__ int   s_nnz;
  __shared__ float s_den;
  const int tid = threadIdx.x;
  const int k = blockIdx.x >> 2, chunk = blockIdx.x & 3;   // 8 blocks: 2k x 4 chunks of 256 d
  if (tid == 0) { s_nnz = 0; s_den = 0.f; }
  __syncthreads();
  const int q0 = qt[0];
  float lsum = 0.f;
#pragma unroll
  for (int i = 0; i < 4; i++) {
    int c = tid * 4 + i;
    float v = onehot[(size_t)q0 * 1024 + c];
    lsum += v;
    if (v != 0.f) { int p = atomicAdd(&s_nnz, 1); aidx[p] = c; a0v[p] = v; }
  }
#pragma unroll
  for (int off = 32; off >= 1; off >>= 1) lsum += __shfl_xor(lsum, off, 64);
  if ((tid & 63) == 0) atomicAdd(&s_den, lsum);
  __syncthreads();
  const float denom = fmaxf(s_den, 1.f);
  const int nnz = s_nnz;
  const int d = chunk * 256 + tid;
  const float* G = graphs + (size_t)k * 1048576 + d;
  float sum = 0.f;
  for (int j = 0; j < nnz; j++) sum += a0v[j] * G[(size_t)aidx[j] * 1024];
  adjw[k * 1024 + d] = fminf(fmaxf(sum / denom, -5.f), 5.f);
}

// ---------------- prep 2: per-c bias tables (kc folded into layer-1 bias) ----------------
// biasTab layout: [c16(64)][tab(3: n_k0,n_k1,self)][nt(4)][lane(64)][r(4)] fp32
__global__ void prep_bias_kernel(const float* __restrict__ kc, const float* __restrict__ Wn1,
                                 const float* __restrict__ bn1, const float* __restrict__ Ws1,
                                 const float* __restrict__ bs1, float* __restrict__ biasTab) {
  int gid = blockIdx.x * 256 + threadIdx.x;   // 196608 total
  int j = gid & 63;
  int c = (gid >> 6) & 1023;
  int tab = gid >> 16;                        // 0,1 neigh-k; 2 self
  const float* kcr = kc + (size_t)c * 64;
  float s;
  if (tab < 2) {
    s = bn1[tab * 64 + j];
    const float* W = Wn1 + ((size_t)tab * 256 + 192) * 64 + j;   // kc rows of neigh net
#pragma unroll 4
    for (int e = 0; e < 64; e++) s += fminf(fmaxf(kcr[e], -5.f), 5.f) * W[(size_t)e * 64];
  } else {
    s = bs1[j];
    const float* W = Ws1 + (size_t)64 * 64 + j;                  // kc rows of self net (unclipped)
#pragma unroll 4
    for (int e = 0; e < 64; e++) s += kcr[e] * W[(size_t)e * 64];
  }
  int c16 = c >> 4, rr = c & 3, qq = (c & 15) >> 2, nt = j >> 4;
  int lane = qq * 16 + (j & 15);
  biasTab[(size_t)((((c16 * 3 + tab) * 4 + nt) * 64 + lane)) * 4 + rr] = s;
}

// ---------------- prep 3: weights -> bf16 B-fragments (pre-swizzled) ----------------
// B-frag (16x16x32): lane l holds B[k = ks*32 + (l>>4)*8 + j][n = nt*16 + (l&15)], j=0..7
__global__ void prep_wfrag_kernel(const float* __restrict__ Wn1, const float* __restrict__ Wn2,
                                  const float* __restrict__ Ws1, const float* __restrict__ Ws2,
                                  const float* __restrict__ We,  const float* __restrict__ Wa,
                                  const float* __restrict__ Wih, const float* __restrict__ Whh,
                                  uint4* __restrict__ wfrag) {
  const int bid = blockIdx.x, lane = threadIdx.x;   // 112 blocks x 64 threads
  int mat, ks, nt;
  if (bid < 64) { mat = bid >> 3; ks = (bid >> 2) & 1; nt = bid & 3; }
  else { int f2 = bid - 64; mat = 8 + f2 / 24; int f = f2 % 24; ks = f / 12; nt = f % 12; }
  const float* base = Wn1; int stride = 64;
  switch (mat) {
    case 0: base = Wn1 + (size_t)128 * 64; break;          // Wn1 k0, ht rows 128..191
    case 1: base = Wn1 + (size_t)(256 + 128) * 64; break;  // Wn1 k1
    case 2: base = Wn2; break;
    case 3: base = Wn2 + (size_t)64 * 64; break;
    case 4: base = Ws1; break;                             // rows 0..63 (ht part)
    case 5: base = Ws2; break;
    case 6: base = We; break;
    case 7: base = Wa; break;
    case 8: base = Wih; stride = 192; break;
    case 9: base = Whh; stride = 192; break;
  }
  const int qq = lane >> 4, col = nt * 16 + (lane & 15);
  union { unsigned short u[8]; uint4 v; } tmp;
#pragma unroll
  for (int jj = 0; jj < 8; jj++) {
    int k = ks * 32 + qq * 8 + jj;
    tmp.u[jj] = bf16r(base[(size_t)k * stride + col]);
  }
  wfrag[(size_t)bid * 64 + lane] = tmp.v;
}

// ---------------- main fused kernel ----------------
// block = 256 threads = 4 waves; each wave owns 32 tokens (2 MFMA m-tiles).
// REGISTER MODEL (rounds 3/6/8): structural unified peak ~188; ANY cap < 256 spills
// 100-500 MB. Pinned at (256,2) = 2 blocks/CU, occupancy ~20% -- final.
// ROUND 9 change: the 48 GRU frags (Wih+Whh, 48 KB) are staged in LDS once per block
// (4x reuse) -- cuts per-wave L2 frag traffic 96->60 KB and converts the GRU's 48
// dependent ~200cy L2 loads into ~120cy LDS reads. LDS total 69.6 KB <= 80 KB/block.
__global__ __launch_bounds__(256, 2) void gkt_main_kernel(
    const int* __restrict__ qt, const float* __restrict__ onehot, const float* __restrict__ ht,
    const float* __restrict__ nw, const float* __restrict__ bn2, const float* __restrict__ be,
    const float* __restrict__ ba, const float* __restrict__ bih, const float* __restrict__ bhh,
    const float* __restrict__ Wp, const float* __restrict__ bp, const float* __restrict__ eaw,
    const float* __restrict__ bs2, const float* __restrict__ adjw, const float* __restrict__ biasTab,
    const bf16x8* __restrict__ wfrag, float* __restrict__ out) {
  __shared__ __align__(16) unsigned short hbuf[4][32][72];  // per-wave stage scratch, bf16, pitch 72
  __shared__ __align__(16) float tokp[4][128];              // [wave][mask|adj0|adj1|g][32]
  __shared__ __align__(16) uint4 gfrag[48 * 64];            // GRU frags: Wih(0..23), Whh(24..47)

  const int tid = threadIdx.x;
  const int wv = tid >> 6, lane = tid & 63;
  const int q = lane >> 4, cl = lane & 15;
  const int t0 = (blockIdx.x * 4 + wv) * 32;
  const int b = t0 >> 10, c0 = t0 & 1023, c16 = c0 >> 4;

  unsigned short* hb = &hbuf[wv][0][0];
  float* tp = &tokp[wv][0];

  // ---- cooperative: GRU frags -> LDS (12 per wave, once per block) ----
  {
    const uint4* wf4 = (const uint4*)wfrag;
#pragma unroll
    for (int i = 0; i < 12; i++) {
      int f = wv * 12 + i;
      gfrag[f * 64 + lane] = wf4[(FB_Wih + f) * 64 + lane];
    }
  }

  // ---- staging: per-token params + ht rows (coalesced float4) ----
  if (lane < 32) {
    const int c = c0 + lane;
    tp[lane]      = onehot[(size_t)qt[b] * 1024 + c];  // mask
    tp[32 + lane] = adjw[c];                           // adj[0][c]
    tp[64 + lane] = adjw[1024 + c];                    // adj[1][c]
    tp[96 + lane] = eaw[c];                            // g
  }
  {
    const float4* ht4 = (const float4*)ht;
#pragma unroll
    for (int i = 0; i < 8; i++) {
      float4 v = ht4[(size_t)t0 * 16 + i * 64 + lane];
      int e = i * 64 + lane;
      int tok = e >> 4, coll = (e & 15) * 4;
      ushort4 h;
      h.x = bf16r(v.x); h.y = bf16r(v.y); h.z = bf16r(v.z); h.w = bf16r(v.w);
      *(ushort4*)&hbuf[wv][tok][coll] = h;
    }
  }
  __syncthreads();   // all staging visible (subsumes per-wave fence; gfrag read-only after)

  const float wmix = fminf(fmaxf(nw[0], 0.1f), 0.9f);
  float wp4[4];
#pragma unroll
  for (int nt = 0; nt < 4; nt++) wp4[nt] = Wp[nt * 16 + cl];
  const float bpv = bp[0];

  auto ldA = [&](int mt, int ks) -> bf16x8 {
    return *(const bf16x8*)(hb + (cl + 16 * mt) * 72 + ks * 32 + q * 8);
  };
  auto ldB = [&](int frag) -> bf16x8 { return wfrag[frag * 64 + lane]; };
  auto ldG = [&](int fr) -> bf16x8 {   // fr in [0,48): 0..23 = Wih, 24..47 = Whh
    return *(const bf16x8*)&gfrag[fr * 64 + lane];
  };
  auto ldTP4 = [&](int base, int mt) -> f32x4 {   // 4 consecutive token params (r=0..3)
    return *(const f32x4*)(tp + base + 16 * mt + q * 4);
  };
  const f32x4* bt4 = (const f32x4*)biasTab;

  // ---- read raw ht A-frags into registers (live through GRU) ----
  bf16x8 xr[2][2];
#pragma unroll
  for (int mt = 0; mt < 2; mt++)
#pragma unroll
    for (int ks = 0; ks < 2; ks++) xr[mt][ks] = ldA(mt, ks);
  lds_fence();   // reads drained; hbuf free for reuse

  // ---- neighbor path (always; for mask==1 tokens result is discarded later) ----
  f32x4 nf[2][4];
  {
    bf16x8 xc[2][2];
#pragma unroll
    for (int mt = 0; mt < 2; mt++)
#pragma unroll
      for (int ks = 0; ks < 2; ks++) xc[mt][ks] = clip5(xr[mt][ks]);

#pragma unroll
    for (int k2 = 0; k2 < 2; k2++) {
      f32x4 acc[2][4];
#pragma unroll
      for (int mt = 0; mt < 2; mt++)
#pragma unroll
        for (int nt = 0; nt < 4; nt++)
          acc[mt][nt] = bt4[(((c16 + mt) * 3 + k2) * 4 + nt) * 64 + lane];  // kc part + bn1
#pragma unroll
      for (int ks = 0; ks < 2; ks++)
#pragma unroll
        for (int nt = 0; nt < 4; nt++) {
          bf16x8 bb = ldB((k2 ? FB_Wn1h1 : FB_Wn1h0) + ks * 4 + nt);
          acc[0][nt] = mfma16(xc[0][ks], bb, acc[0][nt]);
          acc[1][nt] = mfma16(xc[1][ks], bb, acc[1][nt]);
        }
#pragma unroll
      for (int mt = 0; mt < 2; mt++)
#pragma unroll
        for (int nt = 0; nt < 4; nt++)
#pragma unroll
          for (int r = 0; r < 4; r++)
            hb[(16 * mt + q * 4 + r) * 72 + nt * 16 + cl] = bf16r(fmaxf(acc[mt][nt][r], 0.f));
      lds_fence();
      f32x4 acc2[2][4];
#pragma unroll
      for (int nt = 0; nt < 4; nt++) {
        float bz = bn2[k2 * 64 + nt * 16 + cl];
        f32x4 iv = {bz, bz, bz, bz};
        acc2[0][nt] = iv; acc2[1][nt] = iv;
      }
#pragma unroll
      for (int ks = 0; ks < 2; ks++) {
        bf16x8 a0 = ldA(0, ks), a1 = ldA(1, ks);
#pragma unroll
        for (int nt = 0; nt < 4; nt++) {
          bf16x8 bb = ldB((k2 ? FB_Wn2_1 : FB_Wn2_0) + ks * 4 + nt);
          acc2[0][nt] = mfma16(a0, bb, acc2[0][nt]);
          acc2[1][nt] = mfma16(a1, bb, acc2[1][nt]);
        }
      }
      lds_fence();   // layer-2 reads drained before next overwrite of hbuf
#pragma unroll
      for (int mt = 0; mt < 2; mt++) {
        f32x4 adjv = ldTP4((1 + k2) * 32, mt);
#pragma unroll
        for (int nt = 0; nt < 4; nt++)
#pragma unroll
          for (int r = 0; r < 4; r++) {
            float nb = fminf(fmaxf(acc2[mt][nt][r], 0.f), 5.f);      // relu then clip
            float v = adjv[r] * nb;                                  // adj[k][c] * nb
            if (k2 == 0) nf[mt][nt][r] = wmix * fminf(fmaxf(v, -5.f), 5.f);
            else         nf[mt][nt][r] = fminf(fmaxf(nf[mt][nt][r] + (1.f - wmix) * v, -5.f), 5.f);
          }
      }
    }
  }

  // ---- self path (only if any of this wave's 32 tokens has mask==1) ----
  bool anySelf = __any((lane < 32) && (tp[lane] > 0.5f));
  if (anySelf) {
    f32x4 acc[2][4];
#pragma unroll
    for (int mt = 0; mt < 2; mt++)
#pragma unroll
      for (int nt = 0; nt < 4; nt++)
        acc[mt][nt] = bt4[(((c16 + mt) * 3 + 2) * 4 + nt) * 64 + lane];
#pragma unroll
    for (int ks = 0; ks < 2; ks++)
#pragma unroll
      for (int nt = 0; nt < 4; nt++) {
        bf16x8 bb = ldB(FB_Ws1h + ks * 4 + nt);
        acc[0][nt] = mfma16(xr[0][ks], bb, acc[0][nt]);    // raw (unclipped) ht
        acc[1][nt] = mfma16(xr[1][ks], bb, acc[1][nt]);
      }
#pragma unroll
    for (int mt = 0; mt < 2; mt++)
#pragma unroll
      for (int nt = 0; nt < 4; nt++)
#pragma unroll
        for (int r = 0; r < 4; r++)
          hb[(16 * mt + q * 4 + r) * 72 + nt * 16 + cl] = bf16r(fmaxf(acc[mt][nt][r], 0.f));
    lds_fence();
    f32x4 acc2[2][4];
#pragma unroll
    for (int nt = 0; nt < 4; nt++) {
      float bz = bs2[nt * 16 + cl];
      f32x4 iv = {bz, bz, bz, bz};
      acc2[0][nt] = iv; acc2[1][nt] = iv;
    }
#pragma unroll
    for (int ks = 0; ks < 2; ks++) {
      bf16x8 a0 = ldA(0, ks), a1 = ldA(1, ks);
#pragma unroll
      for (int nt = 0; nt < 4; nt++) {
        bf16x8 bb = ldB(FB_Ws2 + ks * 4 + nt);
        acc2[0][nt] = mfma16(a0, bb, acc2[0][nt]);
        acc2[1][nt] = mfma16(a1, bb, acc2[1][nt]);
      }
    }
    lds_fence();
#pragma unroll
    for (int mt = 0; mt < 2; mt++) {
      f32x4 mk = ldTP4(0, mt);
#pragma unroll
      for (int nt = 0; nt < 4; nt++)
#pragma unroll
        for (int r = 0; r < 4; r++) {
          float sf = fminf(fmaxf(acc2[mt][nt][r], 0.f), 10.f);   // relu, clip +-10
          nf[mt][nt][r] = (mk[r] > 0.5f) ? sf : nf[mt][nt][r];   // m_next select (clip50 identity)
        }
    }
  }

  // ---- res = m - g*sigmoid(m@We+be)*m + g*tanh(m@Wa+ba)  (mt-PARALLEL) ----
#pragma unroll
  for (int mt = 0; mt < 2; mt++)
#pragma unroll
    for (int nt = 0; nt < 4; nt++)
#pragma unroll
      for (int r = 0; r < 4; r++)
        hb[(16 * mt + q * 4 + r) * 72 + nt * 16 + cl] = bf16r(nf[mt][nt][r]);  // m_next (bf16)
  lds_fence();
  bf16x8 mf[2][2];
#pragma unroll
  for (int mt = 0; mt < 2; mt++)
#pragma unroll
    for (int ks = 0; ks < 2; ks++) mf[mt][ks] = ldA(mt, ks);
  lds_fence();
  {
    f32x4 accE[2][4];
#pragma unroll
    for (int nt = 0; nt < 4; nt++) {
      float bz = be[nt * 16 + cl];
      f32x4 iv = {bz, bz, bz, bz};
      accE[0][nt] = iv; accE[1][nt] = iv;
    }
#pragma unroll
    for (int ks = 0; ks < 2; ks++)
#pragma unroll
      for (int nt = 0; nt < 4; nt++) {
        bf16x8 bb = ldB(FB_We + ks * 4 + nt);
        accE[0][nt] = mfma16(mf[0][ks], bb, accE[0][nt]);
        accE[1][nt] = mfma16(mf[1][ks], bb, accE[1][nt]);
      }
#pragma unroll
    for (int mt = 0; mt < 2; mt++) {
      f32x4 gv = ldTP4(96, mt);
#pragma unroll
      for (int nt = 0; nt < 4; nt++)
#pragma unroll
        for (int r = 0; r < 4; r++) {
          float m = nf[mt][nt][r];
          nf[mt][nt][r] = m - gv[r] * sigmoidf_(accE[mt][nt][r]) * m;
        }
    }
    f32x4 accA[2][4];
#pragma unroll
    for (int nt = 0; nt < 4; nt++) {
      float bz = ba[nt * 16 + cl];
      f32x4 iv = {bz, bz, bz, bz};
      accA[0][nt] = iv; accA[1][nt] = iv;
    }
#pragma unroll
    for (int ks = 0; ks < 2; ks++)
#pragma unroll
      for (int nt = 0; nt < 4; nt++) {
        bf16x8 bb = ldB(FB_Wa + ks * 4 + nt);
        accA[0][nt] = mfma16(mf[0][ks], bb, accA[0][nt]);
        accA[1][nt] = mfma16(mf[1][ks], bb, accA[1][nt]);
      }
#pragma unroll
    for (int mt = 0; mt < 2; mt++) {
      f32x4 gv = ldTP4(96, mt);
#pragma unroll
      for (int nt = 0; nt < 4; nt++)
#pragma unroll
        for (int r = 0; r < 4; r++)
          nf[mt][nt][r] += gv[r] * tanhf_(accA[mt][nt][r]);   // nf now holds res
    }
  }

  // ---- GRU gates + output (mt-PARALLEL; frags from LDS) ----
#pragma unroll
  for (int mt = 0; mt < 2; mt++)
#pragma unroll
    for (int nt = 0; nt < 4; nt++)
#pragma unroll
      for (int r = 0; r < 4; r++)
        hb[(16 * mt + q * 4 + r) * 72 + nt * 16 + cl] = bf16r(nf[mt][nt][r]);  // res (bf16)
  lds_fence();
  bf16x8 rf[2][2];
#pragma unroll
  for (int mt = 0; mt < 2; mt++)
#pragma unroll
    for (int ks = 0; ks < 2; ks++) rf[mt][ks] = ldA(mt, ks);

  f32x4 gR[2][4], gZ[2][4], gN[2][4], gH[2][4];
#pragma unroll
  for (int nt = 0; nt < 4; nt++) {
    int col = nt * 16 + cl;
    float brz = bih[col] + bhh[col];
    float bzz = bih[64 + col] + bhh[64 + col];
    float bnn = bih[128 + col];
    float bhn = bhh[128 + col];
    f32x4 v;
    v = {brz, brz, brz, brz}; gR[0][nt] = v; gR[1][nt] = v;
    v = {bzz, bzz, bzz, bzz}; gZ[0][nt] = v; gZ[1][nt] = v;
    v = {bnn, bnn, bnn, bnn}; gN[0][nt] = v; gN[1][nt] = v;
    v = {bhn, bhn, bhn, bhn}; gH[0][nt] = v; gH[1][nt] = v;
  }
#pragma unroll
  for (int ks = 0; ks < 2; ks++)
#pragma unroll
    for (int nt = 0; nt < 4; nt++) {
      bf16x8 bi_r = ldG(ks * 12 + nt);
      bf16x8 bh_r = ldG(24 + ks * 12 + nt);
      bf16x8 bi_z = ldG(ks * 12 + 4 + nt);
      bf16x8 bh_z = ldG(24 + ks * 12 + 4 + nt);
      bf16x8 bi_n = ldG(ks * 12 + 8 + nt);
      bf16x8 bh_n = ldG(24 + ks * 12 + 8 + nt);
#pragma unroll
      for (int mt = 0; mt < 2; mt++) {
        gR[mt][nt] = mfma16(rf[mt][ks], bi_r, gR[mt][nt]);
        gR[mt][nt] = mfma16(xr[mt][ks], bh_r, gR[mt][nt]);   // gi_r + gh_r chained
        gZ[mt][nt] = mfma16(rf[mt][ks], bi_z, gZ[mt][nt]);
        gZ[mt][nt] = mfma16(xr[mt][ks], bh_z, gZ[mt][nt]);
        gN[mt][nt] = mfma16(rf[mt][ks], bi_n, gN[mt][nt]);   // in_
        gH[mt][nt] = mfma16(xr[mt][ks], bh_n, gH[mt][nt]);   // hn
      }
    }

#pragma unroll
  for (int mt = 0; mt < 2; mt++)
#pragma unroll
    for (int r = 0; r < 4; r++) {
      int tok = 16 * mt + q * 4 + r;
      float part = 0.f;
#pragma unroll
      for (int nt = 0; nt < 4; nt++) {
        float rr = sigmoidf_(gR[mt][nt][r]);
        float zz = sigmoidf_(gZ[mt][nt][r]);
        float nval = tanhf_(gN[mt][nt][r] + rr * gH[mt][nt][r]);
        float htv = ht[(size_t)(t0 + tok) * 64 + nt * 16 + cl];   // fp32 ht for blend
        float hnx = (1.f - zz) * nval + zz * htv;
        part += hnx * wp4[nt];
      }
      part += __shfl_xor(part, 1, 64);
      part += __shfl_xor(part, 2, 64);
      part += __shfl_xor(part, 4, 64);
      part += __shfl_xor(part, 8, 64);
      if (cl == 0) out[t0 + tok] = sigmoidf_(part + bpv);
    }
}

// ---------------- launcher ----------------
extern "C" void kernel_launch(void* const* d_in, const int* in_sizes, int n_in,
                              void* d_out, int out_size, void* d_ws, size_t ws_size,
                              hipStream_t stream) {
  const int*   qt     = (const int*)d_in[1];
  const float* ht     = (const float*)d_in[2];
  const float* onehot = (const float*)d_in[3];
  const float* kc     = (const float*)d_in[4];
  const float* graphs = (const float*)d_in[5];
  const float* nw     = (const float*)d_in[6];
  const float* Ws1    = (const float*)d_in[7];
  const float* bs1    = (const float*)d_in[8];
  const float* Ws2    = (const float*)d_in[9];
  const float* bs2    = (const float*)d_in[10];
  const float* Wn1    = (const float*)d_in[11];
  const float* bn1    = (const float*)d_in[12];
  const float* Wn2    = (const float*)d_in[13];
  const float* bn2    = (const float*)d_in[14];
  const float* eaw    = (const float*)d_in[15];
  const float* We     = (const float*)d_in[16];
  const float* be     = (const float*)d_in[17];
  const float* Wa     = (const float*)d_in[18];
  const float* ba     = (const float*)d_in[19];
  const float* Wih    = (const float*)d_in[20];
  const float* bih    = (const float*)d_in[21];
  const float* Whh    = (const float*)d_in[22];
  const float* bhh    = (const float*)d_in[23];
  const float* Wp     = (const float*)d_in[24];
  const float* bp     = (const float*)d_in[25];
  float* out = (float*)d_out;

  float* adjw    = (float*)((char*)d_ws + kAdjOff);
  float* biasTab = (float*)((char*)d_ws + kBiasOff);
  uint4* wfragU  = (uint4*)((char*)d_ws + kFragOff);

  prep_adj_kernel<<<8, 256, 0, stream>>>(qt, onehot, graphs, adjw);
  prep_bias_kernel<<<768, 256, 0, stream>>>(kc, Wn1, bn1, Ws1, bs1, biasTab);
  prep_wfrag_kernel<<<112, 64, 0, stream>>>(Wn1, Wn2, Ws1, Ws2, We, Wa, Wih, Whh, wfragU);
  gkt_main_kernel<<<2048, 256, 0, stream>>>(qt, onehot, ht, nw, bn2, be, ba, bih, bhh,
                                            Wp, bp, eaw, bs2, adjw, biasTab,
                                            (const bf16x8*)wfragU, out);
}